// Round 1
// baseline (169.027 us; speedup 1.0000x reference)
//
#include <hip/hip_runtime.h>

#define IN_F   100000
#define OUT_F  100000
#define NNZ_N  1600000
#define BATCH  64

// ---------------------------------------------------------------------------
// Kernel 1: transpose x (B=64, IN) -> x_t (IN, 64) so per-edge batch gathers
// become one contiguous 256B segment.
// ---------------------------------------------------------------------------
__global__ __launch_bounds__(256) void k_transpose_x(
    const float* __restrict__ x, float* __restrict__ xt, int in_f) {
    __shared__ float tile[64][65];   // +1 pad: conflict-free both phases
    const int i0 = blockIdx.x * 64;
    const int t  = threadIdx.x;      // 0..255
    const int c  = t & 63;           // lane
    const int q  = t >> 6;           // wave id 0..3

    // read phase: coalesced along IN
    for (int bb = q; bb < 64; bb += 4) {
        const int col = i0 + c;
        tile[bb][c] = (col < in_f) ? x[(size_t)bb * in_f + col] : 0.f;
    }
    __syncthreads();
    // write phase: coalesced along x_t rows (256B per wave)
    const int b = c;
    for (int cc = q; cc < 64; cc += 4) {
        const int col = i0 + cc;
        if (col < in_f) xt[(size_t)col * 64 + b] = tile[b][cc];
    }
}

// ---------------------------------------------------------------------------
// Kernel 2: per-row SpMM. Block = 256 threads = 4 waves handles 64 consecutive
// output rows. lane = batch index. Row boundaries via binary search on sorted
// `rows` (65 searches -> LDS). Output staged in LDS tile then written
// coalesced into (B, OUT) layout with bias added.
// TRANSPOSED=1: gather from x_t (IN,64). TRANSPOSED=0: fallback from x (B,IN).
// ---------------------------------------------------------------------------
template <int TRANSPOSED>
__global__ __launch_bounds__(256) void k_spmm(
    const float* __restrict__ xsrc,       // x_t if TRANSPOSED else x
    const float* __restrict__ vals,
    const int*   __restrict__ rows,
    const int*   __restrict__ cols,
    const float* __restrict__ bias,
    float* __restrict__ out) {
    __shared__ int   rstart[65];
    __shared__ float tile[64][65];        // [local_row][batch], padded

    const int r0   = blockIdx.x * 64;
    const int t    = threadIdx.x;
    const int lane = t & 63;
    const int w    = t >> 6;

    // --- 65 lower_bound searches for row segment boundaries ---
    if (t < 65) {
        const int target = r0 + t;
        int lo = 0, hi = NNZ_N;
        while (lo < hi) {
            const int mid = (lo + hi) >> 1;
            if (rows[mid] < target) lo = mid + 1; else hi = mid;
        }
        rstart[t] = lo;
    }
    __syncthreads();

    // --- accumulate: wave w handles rows j = w, w+4, ... (interleaved for balance)
    for (int j = w; j < 64; j += 4) {
        const int r = r0 + j;
        float acc = 0.f;
        if (r < OUT_F) {
            int s = __builtin_amdgcn_readfirstlane(rstart[j]);
            int e = __builtin_amdgcn_readfirstlane(rstart[j + 1]);
            int idx = s;
            // unroll-by-4 for load ILP (col load -> dependent gather)
            for (; idx + 4 <= e; idx += 4) {
                const int c0 = cols[idx    ];
                const int c1 = cols[idx + 1];
                const int c2 = cols[idx + 2];
                const int c3 = cols[idx + 3];
                const float v0 = vals[idx    ];
                const float v1 = vals[idx + 1];
                const float v2 = vals[idx + 2];
                const float v3 = vals[idx + 3];
                float x0, x1, x2, x3;
                if (TRANSPOSED) {
                    x0 = xsrc[(size_t)c0 * 64 + lane];
                    x1 = xsrc[(size_t)c1 * 64 + lane];
                    x2 = xsrc[(size_t)c2 * 64 + lane];
                    x3 = xsrc[(size_t)c3 * 64 + lane];
                } else {
                    const size_t base = (size_t)lane * IN_F;
                    x0 = xsrc[base + c0];
                    x1 = xsrc[base + c1];
                    x2 = xsrc[base + c2];
                    x3 = xsrc[base + c3];
                }
                acc = fmaf(v0, x0, acc);
                acc = fmaf(v1, x1, acc);
                acc = fmaf(v2, x2, acc);
                acc = fmaf(v3, x3, acc);
            }
            for (; idx < e; ++idx) {
                const int cc = cols[idx];
                const float xv = TRANSPOSED ? xsrc[(size_t)cc * 64 + lane]
                                            : xsrc[(size_t)lane * IN_F + cc];
                acc = fmaf(vals[idx], xv, acc);
            }
        }
        tile[j][lane] = acc;
    }
    __syncthreads();

    // --- write phase: out[b*OUT + r0 + c] coalesced, + bias ---
    const int c = lane;                 // column offset within the 64-row strip
    if (r0 + c < OUT_F) {
        const float bv = bias[r0 + c];
        for (int bb = w; bb < 64; bb += 4) {
            out[(size_t)bb * OUT_F + (r0 + c)] = tile[c][bb] + bv;
        }
    }
}

extern "C" void kernel_launch(void* const* d_in, const int* in_sizes, int n_in,
                              void* d_out, int out_size, void* d_ws, size_t ws_size,
                              hipStream_t stream) {
    const float* x      = (const float*)d_in[0];
    const float* values = (const float*)d_in[1];
    const float* bias   = (const float*)d_in[2];
    const int*   rows   = (const int*)d_in[3];
    const int*   cols   = (const int*)d_in[4];
    float*       out    = (float*)d_out;

    const size_t xt_bytes = (size_t)IN_F * 64 * sizeof(float);  // 25.6 MB
    const int row_blocks = (OUT_F + 63) / 64;                   // 1563
    const int col_blocks = (IN_F + 63) / 64;                    // 1563

    if (ws_size >= xt_bytes) {
        float* xt = (float*)d_ws;
        k_transpose_x<<<col_blocks, 256, 0, stream>>>(x, xt, IN_F);
        k_spmm<1><<<row_blocks, 256, 0, stream>>>(xt, values, rows, cols, bias, out);
    } else {
        // fallback: uncoalesced gather from native layout (correct, slower)
        k_spmm<0><<<row_blocks, 256, 0, stream>>>(x, values, rows, cols, bias, out);
    }
}